// Round 1
// baseline (991.889 us; speedup 1.0000x reference)
//
#include <hip/hip_runtime.h>
#include <stdint.h>

typedef unsigned short u16;
typedef short short8 __attribute__((ext_vector_type(8)));
typedef float floatx4 __attribute__((ext_vector_type(4)));

#define D_FEAT 256

__device__ __forceinline__ u16 f2bf(float x){
  unsigned u = __float_as_uint(x);
  u += 0x7FFFu + ((u >> 16) & 1u);   // round-to-nearest-even
  return (u16)(u >> 16);
}

__device__ __forceinline__ short8 pack8(float4 a, float4 b){
  short8 v;
  v[0]=(short)f2bf(a.x); v[1]=(short)f2bf(a.y); v[2]=(short)f2bf(a.z); v[3]=(short)f2bf(a.w);
  v[4]=(short)f2bf(b.x); v[5]=(short)f2bf(b.y); v[6]=(short)f2bf(b.z); v[7]=(short)f2bf(b.w);
  return v;
}

// wt[n*K + k] = bf16(w[k*N + n])  -- transpose so B-fragments are contiguous in K
__global__ void conv_t_kernel(const float* __restrict__ w, u16* __restrict__ wt, int K, int N){
  int idx = blockIdx.x * 256 + threadIdx.x;
  if (idx >= K * N) return;
  int k = idx / N, n = idx - k * N;
  wt[(size_t)n * K + k] = f2bf(w[idx]);
}

// ---------------- CSR build ----------------
__global__ void hist_kernel(const int* __restrict__ didx, int E, int* __restrict__ cnt){
  int e = blockIdx.x * 256 + threadIdx.x;
  if (e < E) atomicAdd(&cnt[didx[e]], 1);
}

__global__ void scan_block_kernel(const int* __restrict__ cnt, int* __restrict__ excl,
                                  int* __restrict__ bsums, int N){
  __shared__ int tmp[256];
  int t = threadIdx.x;
  int i = blockIdx.x * 256 + t;
  int v = (i < N) ? cnt[i] : 0;
  tmp[t] = v; __syncthreads();
#pragma unroll
  for (int o = 1; o < 256; o <<= 1){
    int x = (t >= o) ? tmp[t - o] : 0;
    __syncthreads();
    tmp[t] += x;
    __syncthreads();
  }
  if (i < N) excl[i] = tmp[t] - v;
  if (t == 255) bsums[blockIdx.x] = tmp[255];
}

__global__ void scan_bsums_kernel(int* __restrict__ bsums, int nb){
  if (blockIdx.x == 0 && threadIdx.x == 0){
    int acc = 0;
    for (int i = 0; i < nb; i++){ int v = bsums[i]; bsums[i] = acc; acc += v; }
  }
}

__global__ void scan_add_kernel(int* __restrict__ excl, const int* __restrict__ bsums, int N){
  int i = blockIdx.x * 256 + threadIdx.x;
  if (i < N) excl[i] += bsums[blockIdx.x];
}

__global__ void fill_csr_kernel(const int* __restrict__ sidx, const int* __restrict__ didx, int E,
                                const int* __restrict__ row_start, int* __restrict__ fillc,
                                int* __restrict__ esrc){
  int e = blockIdx.x * 256 + threadIdx.x;
  if (e >= E) return;
  int d = didx[e];
  int pos = atomicAdd(&fillc[d], 1);
  esrc[row_start[d] + pos] = sidx[e];
}

// one wave per dst row: gather src rows, accumulate fp32, write mean
__global__ void agg_mean_kernel(const float* __restrict__ feat, const int* __restrict__ row_start,
                                const int* __restrict__ cnt, const int* __restrict__ esrc,
                                float* __restrict__ mean, int M){
  int row = blockIdx.x * 4 + (threadIdx.x >> 6);
  int lane = threadIdx.x & 63;
  if (row >= M) return;
  int beg = row_start[row], n = cnt[row];
  float4 a0 = {0.f,0.f,0.f,0.f}, a1 = {0.f,0.f,0.f,0.f};
  int j = 0;
  for (; j + 1 < n; j += 2){
    int s0 = esrc[beg + j], s1 = esrc[beg + j + 1];
    float4 v0 = ((const float4*)(feat + (size_t)s0 * D_FEAT))[lane];
    float4 v1 = ((const float4*)(feat + (size_t)s1 * D_FEAT))[lane];
    a0.x += v0.x; a0.y += v0.y; a0.z += v0.z; a0.w += v0.w;
    a1.x += v1.x; a1.y += v1.y; a1.z += v1.z; a1.w += v1.w;
  }
  if (j < n){
    int s0 = esrc[beg + j];
    float4 v0 = ((const float4*)(feat + (size_t)s0 * D_FEAT))[lane];
    a0.x += v0.x; a0.y += v0.y; a0.z += v0.z; a0.w += v0.w;
  }
  float inv = 1.0f / fmaxf((float)n, 1.0f);
  float4 o;
  o.x = (a0.x + a1.x) * inv; o.y = (a0.y + a1.y) * inv;
  o.z = (a0.z + a1.z) * inv; o.w = (a0.w + a1.w) * inv;
  ((float4*)(mean + (size_t)row * D_FEAT))[lane] = o;
}

// ---------------- Fused MLP: out = [LN]( resid + relu(concat(h,s)@W1+b1)@W2 + b2 ) ----------------
// Block: 128 rows x 256 cols, 512 threads (8 waves, 2 row x 4 col).
// Phase 1 (K=512) -> hidden (relu, bf16) kept in LDS. Phase 2 (K=256) reads hidden
// straight from LDS (no A restaging). Epilogue fuses bias+resid and optional LayerNorm.
template<int HAS_LN>
__global__ __launch_bounds__(512, 2) void fused_mlp_kernel(
    const float* __restrict__ h, const float* __restrict__ s,
    const u16* __restrict__ B1t, const float* __restrict__ b1,
    const u16* __restrict__ B2t, const float* __restrict__ b2,
    const float* __restrict__ resid,
    const float* __restrict__ lng, const float* __restrict__ lnb,
    float* __restrict__ out, int M)
{
  __shared__ short8 As8[128 * 5];        // 10240 B  (pad 4->5 chunks/row)
  __shared__ short8 Bs8[256 * 5];        // 20480 B
  __shared__ u16 hid[128][264];          // 67584 B  (stride 264: phase-2 reads 2-way = free)
  __shared__ float part[2][128][4];      // 4096 B   (LN cross-wave partials)

  int tid = threadIdx.x;
  int wave = tid >> 6, lane = tid & 63;
  int half = lane >> 4, l16 = lane & 15;
  int wr = (wave >> 2) * 64, wc = (wave & 3) * 64;
  int row0 = blockIdx.x * 128;

  floatx4 acc[4][4];
  floatx4 zero4 = {0.f, 0.f, 0.f, 0.f};
#pragma unroll
  for (int i = 0; i < 4; i++)
#pragma unroll
    for (int j = 0; j < 4; j++) acc[i][j] = zero4;

  // ---- phase 1: hidden = relu(concat(h,s) @ W1 + b1), K=512 ----
  for (int k0 = 0; k0 < 512; k0 += 32){
    {
      int r = tid >> 2, u = tid & 3;     // 512 threads = 128 rows x 4 chunks
      int kk = k0 + u * 8;
      int rg = row0 + r;
      short8 v = {0,0,0,0,0,0,0,0};
      if (rg < M){
        const float* src = (kk < 256) ? (h + (size_t)rg * 256 + kk)
                                      : (s + (size_t)rg * 256 + (kk - 256));
        float4 f0 = ((const float4*)src)[0];
        float4 f1 = ((const float4*)src)[1];
        v = pack8(f0, f1);
      }
      As8[r * 5 + u] = v;
    }
#pragma unroll
    for (int cc = 0; cc < 2; cc++){      // 256 cols x 4 chunks = 1024 -> 2/thread
      int c = tid + cc * 512;
      int r = c >> 2, u = c & 3;
      Bs8[r * 5 + u] = *(const short8*)(B1t + (size_t)r * 512 + k0 + u * 8);
    }
    __syncthreads();
    short8 af[4], bfr[4];
#pragma unroll
    for (int t = 0; t < 4; t++){
      af[t]  = As8[(wr + t * 16 + l16) * 5 + half];
      bfr[t] = Bs8[(wc + t * 16 + l16) * 5 + half];
    }
#pragma unroll
    for (int i = 0; i < 4; i++)
#pragma unroll
      for (int j = 0; j < 4; j++)
        acc[i][j] = __builtin_amdgcn_mfma_f32_16x16x32_bf16(af[i], bfr[j], acc[i][j], 0, 0, 0);
    __syncthreads();
  }

  // hidden -> LDS (bias + relu + bf16). Each wave writes its own 64x64 tile.
#pragma unroll
  for (int i = 0; i < 4; i++){
#pragma unroll
    for (int j = 0; j < 4; j++){
      int cg = wc + j * 16 + l16;
      float bv = b1[cg];
#pragma unroll
      for (int r = 0; r < 4; r++){
        int lr = wr + i * 16 + half * 4 + r;
        hid[lr][cg] = f2bf(fmaxf(acc[i][j][r] + bv, 0.0f));
      }
    }
  }

#pragma unroll
  for (int i = 0; i < 4; i++)
#pragma unroll
    for (int j = 0; j < 4; j++) acc[i][j] = zero4;

  // ---- phase 2: out = hidden @ W2, K=256; A comes straight from hid LDS ----
  for (int k0 = 0; k0 < 256; k0 += 32){
#pragma unroll
    for (int cc = 0; cc < 2; cc++){
      int c = tid + cc * 512;
      int r = c >> 2, u = c & 3;
      Bs8[r * 5 + u] = *(const short8*)(B2t + (size_t)r * 256 + k0 + u * 8);
    }
    __syncthreads();                     // also orders hid writes before first reads
    short8 af[4], bfr[4];
#pragma unroll
    for (int t = 0; t < 4; t++){
      af[t]  = *(const short8*)(&hid[wr + t * 16 + l16][k0 + half * 8]);
      bfr[t] = Bs8[(wc + t * 16 + l16) * 5 + half];
    }
#pragma unroll
    for (int i = 0; i < 4; i++)
#pragma unroll
      for (int j = 0; j < 4; j++)
        acc[i][j] = __builtin_amdgcn_mfma_f32_16x16x32_bf16(af[i], bfr[j], acc[i][j], 0, 0, 0);
    __syncthreads();
  }

  // ---- epilogue: bias + residual ----
#pragma unroll
  for (int i = 0; i < 4; i++){
#pragma unroll
    for (int j = 0; j < 4; j++){
      int cg = wc + j * 16 + l16;
      float bv = b2[cg];
#pragma unroll
      for (int r = 0; r < 4; r++){
        int lr = wr + i * 16 + half * 4 + r;
        int rg = row0 + lr;
        float rv = (rg < M) ? resid[(size_t)rg * 256 + cg] : 0.0f;
        acc[i][j][r] = acc[i][j][r] + bv + rv;
      }
    }
  }

  if (HAS_LN){
    // per-row partial sums over this wave's 64 cols (reduce across the 16-lane group)
#pragma unroll
    for (int i = 0; i < 4; i++){
#pragma unroll
      for (int r = 0; r < 4; r++){
        float s1 = 0.f, s2 = 0.f;
#pragma unroll
        for (int j = 0; j < 4; j++){
          float v = acc[i][j][r];
          s1 += v; s2 += v * v;
        }
#pragma unroll
        for (int m = 1; m < 16; m <<= 1){
          s1 += __shfl_xor(s1, m, 64);
          s2 += __shfl_xor(s2, m, 64);
        }
        if (l16 == 0){
          int lr = wr + i * 16 + half * 4 + r;
          part[0][lr][wave & 3] = s1;
          part[1][lr][wave & 3] = s2;
        }
      }
    }
    __syncthreads();
#pragma unroll
    for (int i = 0; i < 4; i++){
#pragma unroll
      for (int r = 0; r < 4; r++){
        int lr = wr + i * 16 + half * 4 + r;
        int rg = row0 + lr;
        float4 p1 = *(const float4*)part[0][lr];
        float4 p2 = *(const float4*)part[1][lr];
        float su = p1.x + p1.y + p1.z + p1.w;
        float sq = p2.x + p2.y + p2.z + p2.w;
        float mean = su * (1.0f / 256.0f);
        float var = sq * (1.0f / 256.0f) - mean * mean;
        float rs = rsqrtf(var + 1e-5f);
        if (rg < M){
#pragma unroll
          for (int j = 0; j < 4; j++){
            int cg = wc + j * 16 + l16;
            float vv = (acc[i][j][r] - mean) * rs * lng[cg] + lnb[cg];
            out[(size_t)rg * 256 + cg] = vv;
          }
        }
      }
    }
  } else {
#pragma unroll
    for (int i = 0; i < 4; i++){
#pragma unroll
      for (int r = 0; r < 4; r++){
        int lr = wr + i * 16 + half * 4 + r;
        int rg = row0 + lr;
        if (rg < M){
#pragma unroll
          for (int j = 0; j < 4; j++){
            int cg = wc + j * 16 + l16;
            out[(size_t)rg * 256 + cg] = acc[i][j][r];
          }
        }
      }
    }
  }
}

// helper: build CSR + aggregate mean for one stage
static void run_agg(const float* feat, const int* edge, int E, int Ndst,
                    int* cnt, int* row_start, int* fillc, int* bsums, int* esrc,
                    float* mean, hipStream_t stream){
  const int* sidx = edge;
  const int* didx = edge + E;
  hipMemsetAsync(cnt, 0, (size_t)Ndst * 4, stream);
  hipMemsetAsync(fillc, 0, (size_t)Ndst * 4, stream);
  int egrid = (E + 255) / 256;
  hist_kernel<<<egrid, 256, 0, stream>>>(didx, E, cnt);
  int nb = (Ndst + 255) / 256;
  scan_block_kernel<<<nb, 256, 0, stream>>>(cnt, row_start, bsums, Ndst);
  scan_bsums_kernel<<<1, 1, 0, stream>>>(bsums, nb);
  scan_add_kernel<<<nb, 256, 0, stream>>>(row_start, bsums, Ndst);
  fill_csr_kernel<<<egrid, 256, 0, stream>>>(sidx, didx, E, row_start, fillc, esrc);
  agg_mean_kernel<<<(Ndst + 3) / 4, 256, 0, stream>>>(feat, row_start, cnt, esrc, mean, Ndst);
}

extern "C" void kernel_launch(void* const* d_in, const int* in_sizes, int n_in,
                              void* d_out, int out_size, void* d_ws, size_t ws_size,
                              hipStream_t stream){
  const float* cell_h = (const float*)d_in[0];
  const float* net_h  = (const float*)d_in[1];
  const int* e_c2n = (const int*)d_in[2];
  const int* e_n2c = (const int*)d_in[3];
  const int* e_c2c = (const int*)d_in[4];
  const float* w1p[3] = {(const float*)d_in[5], (const float*)d_in[9],  (const float*)d_in[13]};
  const float* b1p[3] = {(const float*)d_in[6], (const float*)d_in[10], (const float*)d_in[14]};
  const float* w2p[3] = {(const float*)d_in[7], (const float*)d_in[11], (const float*)d_in[15]};
  const float* b2p[3] = {(const float*)d_in[8], (const float*)d_in[12], (const float*)d_in[16]};
  const float* net_g  = (const float*)d_in[17];
  const float* net_b  = (const float*)d_in[18];
  const float* cell_g = (const float*)d_in[19];
  const float* cell_b = (const float*)d_in[20];

  int n_cell = in_sizes[0] / 256;
  int n_net  = in_sizes[1] / 256;
  int E = in_sizes[2] / 2;

  float* cell_out = (float*)d_out;
  float* net_out  = (float*)d_out + (size_t)n_cell * 256;

  // workspace layout
  char* p = (char*)d_ws;
  u16* w1t[3]; u16* w2t[3];
  for (int i = 0; i < 3; i++){
    w1t[i] = (u16*)p; p += (size_t)512 * 256 * 2;
    w2t[i] = (u16*)p; p += (size_t)256 * 256 * 2;
  }
  float* Mbuf = (float*)p; p += (size_t)n_cell * 256 * 4;  // fp32 mean
  int n_pad = ((n_cell + 63) / 64) * 64;
  int* cnt       = (int*)p; p += (size_t)n_pad * 4;
  int* row_start = (int*)p; p += (size_t)n_pad * 4;
  int* fillc     = (int*)p; p += (size_t)n_pad * 4;
  int* bsums     = (int*)p; p += 1024 * 4;
  int* esrc      = (int*)p; p += (size_t)E * 4;

  // convert + transpose weights to bf16 [N][K]
  for (int i = 0; i < 3; i++){
    conv_t_kernel<<<(512 * 256 + 255) / 256, 256, 0, stream>>>(w1p[i], w1t[i], 512, 256);
    conv_t_kernel<<<(256 * 256 + 255) / 256, 256, 0, stream>>>(w2p[i], w2t[i], 256, 256);
  }

  dim3 blk(512);

  // ---- stage 1: cells -> nets (LN) ----
  run_agg(cell_h, e_c2n, E, n_net, cnt, row_start, fillc, bsums, esrc, Mbuf, stream);
  fused_mlp_kernel<1><<<dim3((n_net + 127) / 128), blk, 0, stream>>>(
      net_h, Mbuf, w1t[0], b1p[0], w2t[0], b2p[0], net_h, net_g, net_b, net_out, n_net);

  // ---- stage 2: nets -> cells (no LN) ----
  run_agg(net_out, e_n2c, E, n_cell, cnt, row_start, fillc, bsums, esrc, Mbuf, stream);
  fused_mlp_kernel<0><<<dim3((n_cell + 127) / 128), blk, 0, stream>>>(
      cell_h, Mbuf, w1t[1], b1p[1], w2t[1], b2p[1], cell_h, nullptr, nullptr, cell_out, n_cell);

  // ---- stage 3: cells -> cells (LN), in-place on cell_out ----
  run_agg(cell_out, e_c2c, E, n_cell, cnt, row_start, fillc, bsums, esrc, Mbuf, stream);
  fused_mlp_kernel<1><<<dim3((n_cell + 127) / 128), blk, 0, stream>>>(
      cell_out, Mbuf, w1t[2], b1p[2], w2t[2], b2p[2], cell_out, cell_g, cell_b, cell_out, n_cell);
}

// Round 2
// 841.568 us; speedup vs baseline: 1.1786x; 1.1786x over previous
//
#include <hip/hip_runtime.h>
#include <stdint.h>

typedef unsigned short u16;
typedef short short8 __attribute__((ext_vector_type(8)));
typedef float floatx4 __attribute__((ext_vector_type(4)));

#define D_FEAT 256

__device__ __forceinline__ u16 f2bf(float x){
  unsigned u = __float_as_uint(x);
  u += 0x7FFFu + ((u >> 16) & 1u);   // round-to-nearest-even
  return (u16)(u >> 16);
}

__device__ __forceinline__ short8 pack8(float4 a, float4 b){
  short8 v;
  v[0]=(short)f2bf(a.x); v[1]=(short)f2bf(a.y); v[2]=(short)f2bf(a.z); v[3]=(short)f2bf(a.w);
  v[4]=(short)f2bf(b.x); v[5]=(short)f2bf(b.y); v[6]=(short)f2bf(b.z); v[7]=(short)f2bf(b.w);
  return v;
}

// wt[n*K + k] = bf16(w[k*N + n])  -- transpose so B-fragments are contiguous in K
__global__ void conv_t_kernel(const float* __restrict__ w, u16* __restrict__ wt, int K, int N){
  int idx = blockIdx.x * 256 + threadIdx.x;
  if (idx >= K * N) return;
  int k = idx / N, n = idx - k * N;
  wt[(size_t)n * K + k] = f2bf(w[idx]);
}

// ---------------- CSR build ----------------
__global__ void hist_kernel(const int* __restrict__ didx, int E, int* __restrict__ cnt){
  int e = blockIdx.x * 256 + threadIdx.x;
  if (e < E) atomicAdd(&cnt[didx[e]], 1);
}

__global__ void scan_block_kernel(const int* __restrict__ cnt, int* __restrict__ excl,
                                  int* __restrict__ bsums, int N){
  __shared__ int tmp[256];
  int t = threadIdx.x;
  int i = blockIdx.x * 256 + t;
  int v = (i < N) ? cnt[i] : 0;
  tmp[t] = v; __syncthreads();
#pragma unroll
  for (int o = 1; o < 256; o <<= 1){
    int x = (t >= o) ? tmp[t - o] : 0;
    __syncthreads();
    tmp[t] += x;
    __syncthreads();
  }
  if (i < N) excl[i] = tmp[t] - v;
  if (t == 255) bsums[blockIdx.x] = tmp[255];
}

// parallel exclusive scan of block sums (nb <= 512 in practice; serial fallback otherwise)
__global__ void scan_bsums_kernel(int* __restrict__ bsums, int nb){
  __shared__ int tmp[512];
  int t = threadIdx.x;
  if (nb > 512){
    if (t == 0){
      int acc = 0;
      for (int i = 0; i < nb; i++){ int v = bsums[i]; bsums[i] = acc; acc += v; }
    }
    return;
  }
  int v = (t < nb) ? bsums[t] : 0;
  tmp[t] = v; __syncthreads();
#pragma unroll
  for (int o = 1; o < 512; o <<= 1){
    int x = (t >= o) ? tmp[t - o] : 0;
    __syncthreads();
    tmp[t] += x;
    __syncthreads();
  }
  if (t < nb) bsums[t] = tmp[t] - v;
}

__global__ void scan_add_kernel(int* __restrict__ excl, const int* __restrict__ bsums, int N){
  int i = blockIdx.x * 256 + threadIdx.x;
  if (i < N) excl[i] += bsums[blockIdx.x];
}

__global__ void fill_csr_kernel(const int* __restrict__ sidx, const int* __restrict__ didx, int E,
                                const int* __restrict__ row_start, int* __restrict__ fillc,
                                int* __restrict__ esrc){
  int e = blockIdx.x * 256 + threadIdx.x;
  if (e >= E) return;
  int d = didx[e];
  int pos = atomicAdd(&fillc[d], 1);
  esrc[row_start[d] + pos] = sidx[e];
}

// one wave per dst row: gather src rows, accumulate fp32, write mean
__global__ void agg_mean_kernel(const float* __restrict__ feat, const int* __restrict__ row_start,
                                const int* __restrict__ cnt, const int* __restrict__ esrc,
                                float* __restrict__ mean, int M){
  int row = blockIdx.x * 4 + (threadIdx.x >> 6);
  int lane = threadIdx.x & 63;
  if (row >= M) return;
  int beg = row_start[row], n = cnt[row];
  float4 a0 = {0.f,0.f,0.f,0.f}, a1 = {0.f,0.f,0.f,0.f};
  int j = 0;
  for (; j + 1 < n; j += 2){
    int s0 = esrc[beg + j], s1 = esrc[beg + j + 1];
    float4 v0 = ((const float4*)(feat + (size_t)s0 * D_FEAT))[lane];
    float4 v1 = ((const float4*)(feat + (size_t)s1 * D_FEAT))[lane];
    a0.x += v0.x; a0.y += v0.y; a0.z += v0.z; a0.w += v0.w;
    a1.x += v1.x; a1.y += v1.y; a1.z += v1.z; a1.w += v1.w;
  }
  if (j < n){
    int s0 = esrc[beg + j];
    float4 v0 = ((const float4*)(feat + (size_t)s0 * D_FEAT))[lane];
    a0.x += v0.x; a0.y += v0.y; a0.z += v0.z; a0.w += v0.w;
  }
  float inv = 1.0f / fmaxf((float)n, 1.0f);
  float4 o;
  o.x = (a0.x + a1.x) * inv; o.y = (a0.y + a1.y) * inv;
  o.z = (a0.z + a1.z) * inv; o.w = (a0.w + a1.w) * inv;
  ((float4*)(mean + (size_t)row * D_FEAT))[lane] = o;
}

// ---------------- Fused MLP: out = [LN]( resid + relu(concat(h,s)@W1+b1)@W2 + b2 ) ----------------
// Block: 64 rows x 256 cols, 256 threads (4 waves, 1 row x 4 col wave grid).
// LDS = 61.4 KB -> 2 blocks/CU (independent barrier domains overlap each other).
// T14 prefetch: next K-step's global loads issued before current step's MFMA.
template<int HAS_LN>
__global__ __launch_bounds__(256, 2) void fused_mlp_kernel(
    const float* __restrict__ h, const float* __restrict__ s,
    const u16* __restrict__ B1t, const float* __restrict__ b1,
    const u16* __restrict__ B2t, const float* __restrict__ b2,
    const float* __restrict__ resid,
    const float* __restrict__ lng, const float* __restrict__ lnb,
    float* __restrict__ out, int M)
{
  __shared__ short8 As8[64 * 5];         // 5120 B  (pad 4->5 chunks/row)
  __shared__ short8 Bs8[256 * 5];        // 20480 B
  __shared__ u16 hid[64][264];           // 33792 B (stride 264: phase-2 reads 2-way = free)
  __shared__ float part[2][64][4];       // 2048 B  (LN cross-wave partials)

  int tid = threadIdx.x;
  int wave = tid >> 6, lane = tid & 63;
  int half = lane >> 4, l16 = lane & 15;
  int wc = wave * 64;
  int row0 = blockIdx.x * 64;

  // staging coords: A = 64 rows x 4 chunks (1/thread); B = 256 rows x 4 chunks (4/thread)
  int rA = tid >> 2, uA = tid & 3;
  int rgA = row0 + rA;

  floatx4 acc[4][4];
  floatx4 zero4 = {0.f, 0.f, 0.f, 0.f};
#pragma unroll
  for (int i = 0; i < 4; i++)
#pragma unroll
    for (int j = 0; j < 4; j++) acc[i][j] = zero4;

  float4 pa0 = {0.f,0.f,0.f,0.f}, pa1 = {0.f,0.f,0.f,0.f};
  short8 pb[4];

  // ---- phase 1: hidden = relu(concat(h,s) @ W1 + b1), K=512 ----
  {
    // prologue loads (step 0)
    int kk = uA * 8;
    if (rgA < M){
      const float* src = h + (size_t)rgA * 256 + kk;   // kk<256 at step 0
      pa0 = ((const float4*)src)[0];
      pa1 = ((const float4*)src)[1];
    }
#pragma unroll
    for (int cc = 0; cc < 4; cc++){
      int c = tid + cc * 256;
      int r = c >> 2, u = c & 3;
      pb[cc] = *(const short8*)(B1t + (size_t)r * 512 + u * 8);
    }
  }

  for (int k0 = 0; k0 < 512; k0 += 32){
    // write prefetched regs to LDS
    {
      short8 va = {0,0,0,0,0,0,0,0};
      if (rgA < M) va = pack8(pa0, pa1);
      As8[rA * 5 + uA] = va;
    }
#pragma unroll
    for (int cc = 0; cc < 4; cc++){
      int c = tid + cc * 256;
      int r = c >> 2, u = c & 3;
      Bs8[r * 5 + u] = pb[cc];
    }
    __syncthreads();

    // issue next step's global loads (hide under MFMA)
    if (k0 < 480){
      int k0n = k0 + 32;
      int kk = k0n + uA * 8;
      if (rgA < M){
        const float* src = (kk < 256) ? (h + (size_t)rgA * 256 + kk)
                                      : (s + (size_t)rgA * 256 + (kk - 256));
        pa0 = ((const float4*)src)[0];
        pa1 = ((const float4*)src)[1];
      }
#pragma unroll
      for (int cc = 0; cc < 4; cc++){
        int c = tid + cc * 256;
        int r = c >> 2, u = c & 3;
        pb[cc] = *(const short8*)(B1t + (size_t)r * 512 + k0n + u * 8);
      }
    }

    short8 af[4], bfr[4];
#pragma unroll
    for (int t = 0; t < 4; t++){
      af[t]  = As8[(t * 16 + l16) * 5 + half];
      bfr[t] = Bs8[(wc + t * 16 + l16) * 5 + half];
    }
#pragma unroll
    for (int i = 0; i < 4; i++)
#pragma unroll
      for (int j = 0; j < 4; j++)
        acc[i][j] = __builtin_amdgcn_mfma_f32_16x16x32_bf16(af[i], bfr[j], acc[i][j], 0, 0, 0);
    __syncthreads();
  }

  // hidden -> LDS (bias + relu + bf16). Each wave writes its 64x64 tile.
#pragma unroll
  for (int i = 0; i < 4; i++){
#pragma unroll
    for (int j = 0; j < 4; j++){
      int cg = wc + j * 16 + l16;
      float bv = b1[cg];
#pragma unroll
      for (int r = 0; r < 4; r++){
        int lr = i * 16 + half * 4 + r;
        hid[lr][cg] = f2bf(fmaxf(acc[i][j][r] + bv, 0.0f));
      }
    }
  }

#pragma unroll
  for (int i = 0; i < 4; i++)
#pragma unroll
    for (int j = 0; j < 4; j++) acc[i][j] = zero4;

  // ---- phase 2: out = hidden @ W2, K=256; A comes straight from hid LDS ----
#pragma unroll
  for (int cc = 0; cc < 4; cc++){
    int c = tid + cc * 256;
    int r = c >> 2, u = c & 3;
    pb[cc] = *(const short8*)(B2t + (size_t)r * 256 + u * 8);
  }

  for (int k0 = 0; k0 < 256; k0 += 32){
#pragma unroll
    for (int cc = 0; cc < 4; cc++){
      int c = tid + cc * 256;
      int r = c >> 2, u = c & 3;
      Bs8[r * 5 + u] = pb[cc];
    }
    __syncthreads();                     // also orders hid writes before first reads

    if (k0 < 224){
      int k0n = k0 + 32;
#pragma unroll
      for (int cc = 0; cc < 4; cc++){
        int c = tid + cc * 256;
        int r = c >> 2, u = c & 3;
        pb[cc] = *(const short8*)(B2t + (size_t)r * 256 + k0n + u * 8);
      }
    }

    short8 af[4], bfr[4];
#pragma unroll
    for (int t = 0; t < 4; t++){
      af[t]  = *(const short8*)(&hid[t * 16 + l16][k0 + half * 8]);
      bfr[t] = Bs8[(wc + t * 16 + l16) * 5 + half];
    }
#pragma unroll
    for (int i = 0; i < 4; i++)
#pragma unroll
      for (int j = 0; j < 4; j++)
        acc[i][j] = __builtin_amdgcn_mfma_f32_16x16x32_bf16(af[i], bfr[j], acc[i][j], 0, 0, 0);
    __syncthreads();
  }

  // ---- epilogue: bias + residual ----
#pragma unroll
  for (int i = 0; i < 4; i++){
#pragma unroll
    for (int j = 0; j < 4; j++){
      int cg = wc + j * 16 + l16;
      float bv = b2[cg];
#pragma unroll
      for (int r = 0; r < 4; r++){
        int lr = i * 16 + half * 4 + r;
        int rg = row0 + lr;
        float rv = (rg < M) ? resid[(size_t)rg * 256 + cg] : 0.0f;
        acc[i][j][r] = acc[i][j][r] + bv + rv;
      }
    }
  }

  if (HAS_LN){
    // per-row partial sums over this wave's 64 cols (reduce across the 16-lane group)
#pragma unroll
    for (int i = 0; i < 4; i++){
#pragma unroll
      for (int r = 0; r < 4; r++){
        float s1 = 0.f, s2 = 0.f;
#pragma unroll
        for (int j = 0; j < 4; j++){
          float v = acc[i][j][r];
          s1 += v; s2 += v * v;
        }
#pragma unroll
        for (int m = 1; m < 16; m <<= 1){
          s1 += __shfl_xor(s1, m, 64);
          s2 += __shfl_xor(s2, m, 64);
        }
        if (l16 == 0){
          int lr = i * 16 + half * 4 + r;
          part[0][lr][wave] = s1;
          part[1][lr][wave] = s2;
        }
      }
    }
    __syncthreads();
#pragma unroll
    for (int i = 0; i < 4; i++){
#pragma unroll
      for (int r = 0; r < 4; r++){
        int lr = i * 16 + half * 4 + r;
        int rg = row0 + lr;
        float4 p1 = *(const float4*)part[0][lr];
        float4 p2 = *(const float4*)part[1][lr];
        float su = p1.x + p1.y + p1.z + p1.w;
        float sq = p2.x + p2.y + p2.z + p2.w;
        float mean = su * (1.0f / 256.0f);
        float var = sq * (1.0f / 256.0f) - mean * mean;
        float rs = rsqrtf(var + 1e-5f);
        if (rg < M){
#pragma unroll
          for (int j = 0; j < 4; j++){
            int cg = wc + j * 16 + l16;
            float vv = (acc[i][j][r] - mean) * rs * lng[cg] + lnb[cg];
            out[(size_t)rg * 256 + cg] = vv;
          }
        }
      }
    }
  } else {
#pragma unroll
    for (int i = 0; i < 4; i++){
#pragma unroll
      for (int r = 0; r < 4; r++){
        int lr = i * 16 + half * 4 + r;
        int rg = row0 + lr;
        if (rg < M){
#pragma unroll
          for (int j = 0; j < 4; j++){
            int cg = wc + j * 16 + l16;
            out[(size_t)rg * 256 + cg] = acc[i][j][r];
          }
        }
      }
    }
  }
}

// helper: build CSR + aggregate mean for one stage
static void run_agg(const float* feat, const int* edge, int E, int Ndst,
                    int* cnt, int* row_start, int* fillc, int* bsums, int* esrc,
                    float* mean, hipStream_t stream){
  const int* sidx = edge;
  const int* didx = edge + E;
  hipMemsetAsync(cnt, 0, (size_t)Ndst * 4, stream);
  hipMemsetAsync(fillc, 0, (size_t)Ndst * 4, stream);
  int egrid = (E + 255) / 256;
  hist_kernel<<<egrid, 256, 0, stream>>>(didx, E, cnt);
  int nb = (Ndst + 255) / 256;
  scan_block_kernel<<<nb, 256, 0, stream>>>(cnt, row_start, bsums, Ndst);
  scan_bsums_kernel<<<1, 512, 0, stream>>>(bsums, nb);
  scan_add_kernel<<<nb, 256, 0, stream>>>(row_start, bsums, Ndst);
  fill_csr_kernel<<<egrid, 256, 0, stream>>>(sidx, didx, E, row_start, fillc, esrc);
  agg_mean_kernel<<<(Ndst + 3) / 4, 256, 0, stream>>>(feat, row_start, cnt, esrc, mean, Ndst);
}

extern "C" void kernel_launch(void* const* d_in, const int* in_sizes, int n_in,
                              void* d_out, int out_size, void* d_ws, size_t ws_size,
                              hipStream_t stream){
  const float* cell_h = (const float*)d_in[0];
  const float* net_h  = (const float*)d_in[1];
  const int* e_c2n = (const int*)d_in[2];
  const int* e_n2c = (const int*)d_in[3];
  const int* e_c2c = (const int*)d_in[4];
  const float* w1p[3] = {(const float*)d_in[5], (const float*)d_in[9],  (const float*)d_in[13]};
  const float* b1p[3] = {(const float*)d_in[6], (const float*)d_in[10], (const float*)d_in[14]};
  const float* w2p[3] = {(const float*)d_in[7], (const float*)d_in[11], (const float*)d_in[15]};
  const float* b2p[3] = {(const float*)d_in[8], (const float*)d_in[12], (const float*)d_in[16]};
  const float* net_g  = (const float*)d_in[17];
  const float* net_b  = (const float*)d_in[18];
  const float* cell_g = (const float*)d_in[19];
  const float* cell_b = (const float*)d_in[20];

  int n_cell = in_sizes[0] / 256;
  int n_net  = in_sizes[1] / 256;
  int E = in_sizes[2] / 2;

  float* cell_out = (float*)d_out;
  float* net_out  = (float*)d_out + (size_t)n_cell * 256;

  // workspace layout
  char* p = (char*)d_ws;
  u16* w1t[3]; u16* w2t[3];
  for (int i = 0; i < 3; i++){
    w1t[i] = (u16*)p; p += (size_t)512 * 256 * 2;
    w2t[i] = (u16*)p; p += (size_t)256 * 256 * 2;
  }
  float* Mbuf = (float*)p; p += (size_t)n_cell * 256 * 4;  // fp32 mean
  int n_pad = ((n_cell + 63) / 64) * 64;
  int* cnt       = (int*)p; p += (size_t)n_pad * 4;
  int* row_start = (int*)p; p += (size_t)n_pad * 4;
  int* fillc     = (int*)p; p += (size_t)n_pad * 4;
  int* bsums     = (int*)p; p += 1024 * 4;
  int* esrc      = (int*)p; p += (size_t)E * 4;

  // convert + transpose weights to bf16 [N][K]
  for (int i = 0; i < 3; i++){
    conv_t_kernel<<<(512 * 256 + 255) / 256, 256, 0, stream>>>(w1p[i], w1t[i], 512, 256);
    conv_t_kernel<<<(256 * 256 + 255) / 256, 256, 0, stream>>>(w2p[i], w2t[i], 256, 256);
  }

  dim3 blk(256);

  // ---- stage 1: cells -> nets (LN) ----
  run_agg(cell_h, e_c2n, E, n_net, cnt, row_start, fillc, bsums, esrc, Mbuf, stream);
  fused_mlp_kernel<1><<<dim3((n_net + 63) / 64), blk, 0, stream>>>(
      net_h, Mbuf, w1t[0], b1p[0], w2t[0], b2p[0], net_h, net_g, net_b, net_out, n_net);

  // ---- stage 2: nets -> cells (no LN) ----
  run_agg(net_out, e_n2c, E, n_cell, cnt, row_start, fillc, bsums, esrc, Mbuf, stream);
  fused_mlp_kernel<0><<<dim3((n_cell + 63) / 64), blk, 0, stream>>>(
      cell_h, Mbuf, w1t[1], b1p[1], w2t[1], b2p[1], cell_h, nullptr, nullptr, cell_out, n_cell);

  // ---- stage 3: cells -> cells (LN), in-place on cell_out ----
  run_agg(cell_out, e_c2c, E, n_cell, cnt, row_start, fillc, bsums, esrc, Mbuf, stream);
  fused_mlp_kernel<1><<<dim3((n_cell + 63) / 64), blk, 0, stream>>>(
      cell_out, Mbuf, w1t[2], b1p[2], w2t[2], b2p[2], cell_out, cell_g, cell_b, cell_out, n_cell);
}

// Round 3
// 812.497 us; speedup vs baseline: 1.2208x; 1.0358x over previous
//
#include <hip/hip_runtime.h>
#include <stdint.h>

typedef unsigned short u16;
typedef short short8 __attribute__((ext_vector_type(8)));
typedef short short4v __attribute__((ext_vector_type(4)));
typedef float floatx4 __attribute__((ext_vector_type(4)));

#define D_FEAT 256

__device__ __forceinline__ u16 f2bf(float x){
  unsigned u = __float_as_uint(x);
  u += 0x7FFFu + ((u >> 16) & 1u);   // round-to-nearest-even
  return (u16)(u >> 16);
}

__device__ __forceinline__ short8 pack8(float4 a, float4 b){
  short8 v;
  v[0]=(short)f2bf(a.x); v[1]=(short)f2bf(a.y); v[2]=(short)f2bf(a.z); v[3]=(short)f2bf(a.w);
  v[4]=(short)f2bf(b.x); v[5]=(short)f2bf(b.y); v[6]=(short)f2bf(b.z); v[7]=(short)f2bf(b.w);
  return v;
}

// wt[n*K + k] = bf16(w[k*N + n])  -- transpose so B-fragments are contiguous in K
__global__ void conv_t_kernel(const float* __restrict__ w, u16* __restrict__ wt, int K, int N){
  int idx = blockIdx.x * 256 + threadIdx.x;
  if (idx >= K * N) return;
  int k = idx / N, n = idx - k * N;
  wt[(size_t)n * K + k] = f2bf(w[idx]);
}

// ---------------- CSR build ----------------
__global__ void hist_kernel(const int* __restrict__ didx, int E, int* __restrict__ cnt){
  int e = blockIdx.x * 256 + threadIdx.x;
  if (e < E) atomicAdd(&cnt[didx[e]], 1);
}

__global__ void scan_block_kernel(const int* __restrict__ cnt, int* __restrict__ excl,
                                  int* __restrict__ bsums, int N){
  __shared__ int tmp[256];
  int t = threadIdx.x;
  int i = blockIdx.x * 256 + t;
  int v = (i < N) ? cnt[i] : 0;
  tmp[t] = v; __syncthreads();
#pragma unroll
  for (int o = 1; o < 256; o <<= 1){
    int x = (t >= o) ? tmp[t - o] : 0;
    __syncthreads();
    tmp[t] += x;
    __syncthreads();
  }
  if (i < N) excl[i] = tmp[t] - v;
  if (t == 255) bsums[blockIdx.x] = tmp[255];
}

// parallel exclusive scan of block sums (nb <= 512 in practice; serial fallback otherwise)
__global__ void scan_bsums_kernel(int* __restrict__ bsums, int nb){
  __shared__ int tmp[512];
  int t = threadIdx.x;
  if (nb > 512){
    if (t == 0){
      int acc = 0;
      for (int i = 0; i < nb; i++){ int v = bsums[i]; bsums[i] = acc; acc += v; }
    }
    return;
  }
  int v = (t < nb) ? bsums[t] : 0;
  tmp[t] = v; __syncthreads();
#pragma unroll
  for (int o = 1; o < 512; o <<= 1){
    int x = (t >= o) ? tmp[t - o] : 0;
    __syncthreads();
    tmp[t] += x;
    __syncthreads();
  }
  if (t < nb) bsums[t] = tmp[t] - v;
}

__global__ void scan_add_kernel(int* __restrict__ excl, const int* __restrict__ bsums, int N){
  int i = blockIdx.x * 256 + threadIdx.x;
  if (i < N) excl[i] += bsums[blockIdx.x];
}

__global__ void fill_csr_kernel(const int* __restrict__ sidx, const int* __restrict__ didx, int E,
                                const int* __restrict__ row_start, int* __restrict__ fillc,
                                int* __restrict__ esrc){
  int e = blockIdx.x * 256 + threadIdx.x;
  if (e >= E) return;
  int d = didx[e];
  int pos = atomicAdd(&fillc[d], 1);
  esrc[row_start[d] + pos] = sidx[e];
}

// one wave per dst row: gather src rows, accumulate fp32, write mean as bf16
__global__ void agg_mean_kernel(const float* __restrict__ feat, const int* __restrict__ row_start,
                                const int* __restrict__ cnt, const int* __restrict__ esrc,
                                u16* __restrict__ mean, int M){
  int row = blockIdx.x * 4 + (threadIdx.x >> 6);
  int lane = threadIdx.x & 63;
  if (row >= M) return;
  int beg = row_start[row], n = cnt[row];
  float4 a0 = {0.f,0.f,0.f,0.f}, a1 = {0.f,0.f,0.f,0.f};
  int j = 0;
  for (; j + 1 < n; j += 2){
    int s0 = esrc[beg + j], s1 = esrc[beg + j + 1];
    float4 v0 = ((const float4*)(feat + (size_t)s0 * D_FEAT))[lane];
    float4 v1 = ((const float4*)(feat + (size_t)s1 * D_FEAT))[lane];
    a0.x += v0.x; a0.y += v0.y; a0.z += v0.z; a0.w += v0.w;
    a1.x += v1.x; a1.y += v1.y; a1.z += v1.z; a1.w += v1.w;
  }
  if (j < n){
    int s0 = esrc[beg + j];
    float4 v0 = ((const float4*)(feat + (size_t)s0 * D_FEAT))[lane];
    a0.x += v0.x; a0.y += v0.y; a0.z += v0.z; a0.w += v0.w;
  }
  float inv = 1.0f / fmaxf((float)n, 1.0f);
  short4v o;
  o[0] = (short)f2bf((a0.x + a1.x) * inv);
  o[1] = (short)f2bf((a0.y + a1.y) * inv);
  o[2] = (short)f2bf((a0.z + a1.z) * inv);
  o[3] = (short)f2bf((a0.w + a1.w) * inv);
  ((short4v*)(mean + (size_t)row * D_FEAT))[lane] = o;
}

// ---------------- Fused MLP: out = [LN]( resid + relu(concat(h,s)@W1+b1)@W2 + b2 ) ----------------
// Block: 64 rows x 256 cols, 256 threads (4 waves). LDS = 52 KB -> 3 blocks/CU.
// XOR-swizzled LDS (no padding): As8/Bs8 chunk ^= row&3; hid chunk ^= row&7.
// All ds_read_b128 patterns land 8 lanes per 4-bank group (structural minimum).
// T14 prefetch: next K-step's global loads issued before current step's MFMA.
// s (mean) operand arrives as bf16 -> second half of phase-1 staging is a plain copy.
template<int HAS_LN>
__global__ __launch_bounds__(256, 3) void fused_mlp_kernel(
    const float* __restrict__ h, const u16* __restrict__ s,
    const u16* __restrict__ B1t, const float* __restrict__ b1,
    const u16* __restrict__ B2t, const float* __restrict__ b2,
    const float* __restrict__ resid,
    const float* __restrict__ lng, const float* __restrict__ lnb,
    float* __restrict__ out, int M)
{
  __shared__ __align__(16) char smem_raw[53248];
  short8* As8 = (short8*)smem_raw;               // [64*4]   4096 B
  short8* Bs8 = (short8*)(smem_raw + 4096);      // [256*4] 16384 B
  u16*    hid = (u16*)(smem_raw + 20480);        // [64*256] 32768 B (swizzled)
  float*  part = (float*)smem_raw;               // aliases As8 (dead in epilogue): [2][64][4]

  int tid = threadIdx.x;
  int wave = tid >> 6, lane = tid & 63;
  int half = lane >> 4, l16 = lane & 15;
  int wc = wave * 64;
  int row0 = blockIdx.x * 64;

  // staging coords: A = 64 rows x 4 chunks (1/thread); B = 256 rows x 4 chunks (4/thread)
  int rA = tid >> 2, uA = tid & 3;
  int rgA = row0 + rA;
  int aw_idx = (rA << 2) | (uA ^ (rA & 3));      // swizzled A write slot

  floatx4 acc[4][4];
  floatx4 zero4 = {0.f, 0.f, 0.f, 0.f};
#pragma unroll
  for (int i = 0; i < 4; i++)
#pragma unroll
    for (int j = 0; j < 4; j++) acc[i][j] = zero4;

  float4 pa0 = {0.f,0.f,0.f,0.f}, pa1 = {0.f,0.f,0.f,0.f};
  short8 ps = {0,0,0,0,0,0,0,0};
  short8 pbv[4];

  // ---- phase 1: hidden = relu(concat(h,s) @ W1 + b1), K=512 ----
  {
    int kk = uA * 8;                     // step 0 is the h (fp32) half
    if (rgA < M){
      const float* src = h + (size_t)rgA * 256 + kk;
      pa0 = ((const float4*)src)[0];
      pa1 = ((const float4*)src)[1];
    }
#pragma unroll
    for (int cc = 0; cc < 4; cc++){
      int c = tid + cc * 256;
      int r = c >> 2, u = c & 3;
      pbv[cc] = *(const short8*)(B1t + (size_t)r * 512 + u * 8);
    }
  }

  for (int k0 = 0; k0 < 512; k0 += 32){
    // write prefetched regs to LDS (swizzled)
    {
      short8 va = {0,0,0,0,0,0,0,0};
      if (k0 < 256){ if (rgA < M) va = pack8(pa0, pa1); }
      else         { va = ps; }
      As8[aw_idx] = va;
    }
#pragma unroll
    for (int cc = 0; cc < 4; cc++){
      int c = tid + cc * 256;
      int r = c >> 2, u = c & 3;
      Bs8[(r << 2) | (u ^ (r & 3))] = pbv[cc];
    }
    __syncthreads();

    // issue next step's global loads (hide under MFMA)
    if (k0 < 480){
      int k0n = k0 + 32;
      int kk = k0n + uA * 8;
      if (k0n < 256){
        if (rgA < M){
          const float* src = h + (size_t)rgA * 256 + kk;
          pa0 = ((const float4*)src)[0];
          pa1 = ((const float4*)src)[1];
        }
      } else {
        ps = (rgA < M) ? *(const short8*)(s + (size_t)rgA * 256 + (kk - 256))
                       : (short8){0,0,0,0,0,0,0,0};
      }
#pragma unroll
      for (int cc = 0; cc < 4; cc++){
        int c = tid + cc * 256;
        int r = c >> 2, u = c & 3;
        pbv[cc] = *(const short8*)(B1t + (size_t)r * 512 + k0n + u * 8);
      }
    }

    short8 af[4], bfr[4];
#pragma unroll
    for (int t = 0; t < 4; t++){
      int ra = t * 16 + l16;
      af[t] = As8[(ra << 2) | (half ^ (ra & 3))];
      int rb = wc + t * 16 + l16;
      bfr[t] = Bs8[(rb << 2) | (half ^ (rb & 3))];
    }
#pragma unroll
    for (int i = 0; i < 4; i++)
#pragma unroll
      for (int j = 0; j < 4; j++)
        acc[i][j] = __builtin_amdgcn_mfma_f32_16x16x32_bf16(af[i], bfr[j], acc[i][j], 0, 0, 0);
    __syncthreads();
  }

  // hidden -> LDS (bias + relu + bf16), swizzled: chunk ^= row&7
#pragma unroll
  for (int i = 0; i < 4; i++){
#pragma unroll
    for (int j = 0; j < 4; j++){
      int cg = wc + j * 16 + l16;
      float bv = b1[cg];
#pragma unroll
      for (int r = 0; r < 4; r++){
        int lr = i * 16 + half * 4 + r;
        int idx = lr * 256 + ((((cg >> 3) ^ (lr & 7)) << 3) | (cg & 7));
        hid[idx] = f2bf(fmaxf(acc[i][j][r] + bv, 0.0f));
      }
    }
  }

#pragma unroll
  for (int i = 0; i < 4; i++)
#pragma unroll
    for (int j = 0; j < 4; j++) acc[i][j] = zero4;

  // ---- phase 2: out = hidden @ W2, K=256; A comes straight from hid LDS ----
#pragma unroll
  for (int cc = 0; cc < 4; cc++){
    int c = tid + cc * 256;
    int r = c >> 2, u = c & 3;
    pbv[cc] = *(const short8*)(B2t + (size_t)r * 256 + u * 8);
  }

  for (int k0 = 0; k0 < 256; k0 += 32){
#pragma unroll
    for (int cc = 0; cc < 4; cc++){
      int c = tid + cc * 256;
      int r = c >> 2, u = c & 3;
      Bs8[(r << 2) | (u ^ (r & 3))] = pbv[cc];
    }
    __syncthreads();                     // also orders hid writes before first reads

    if (k0 < 224){
      int k0n = k0 + 32;
#pragma unroll
      for (int cc = 0; cc < 4; cc++){
        int c = tid + cc * 256;
        int r = c >> 2, u = c & 3;
        pbv[cc] = *(const short8*)(B2t + (size_t)r * 256 + k0n + u * 8);
      }
    }

    short8 af[4], bfr[4];
#pragma unroll
    for (int t = 0; t < 4; t++){
      int ra = t * 16 + l16;
      int chunkL = (k0 >> 3) + half;
      af[t] = *(const short8*)(hid + ra * 256 + ((chunkL ^ (ra & 7)) << 3));
      int rb = wc + t * 16 + l16;
      bfr[t] = Bs8[(rb << 2) | (half ^ (rb & 3))];
    }
#pragma unroll
    for (int i = 0; i < 4; i++)
#pragma unroll
      for (int j = 0; j < 4; j++)
        acc[i][j] = __builtin_amdgcn_mfma_f32_16x16x32_bf16(af[i], bfr[j], acc[i][j], 0, 0, 0);
    __syncthreads();
  }

  // ---- epilogue: bias + residual ----
#pragma unroll
  for (int i = 0; i < 4; i++){
#pragma unroll
    for (int j = 0; j < 4; j++){
      int cg = wc + j * 16 + l16;
      float bv = b2[cg];
#pragma unroll
      for (int r = 0; r < 4; r++){
        int lr = i * 16 + half * 4 + r;
        int rg = row0 + lr;
        float rv = (rg < M) ? resid[(size_t)rg * 256 + cg] : 0.0f;
        acc[i][j][r] = acc[i][j][r] + bv + rv;
      }
    }
  }

  if (HAS_LN){
    // per-row partial sums over this wave's 64 cols (reduce across the 16-lane group)
#pragma unroll
    for (int i = 0; i < 4; i++){
#pragma unroll
      for (int r = 0; r < 4; r++){
        float s1 = 0.f, s2 = 0.f;
#pragma unroll
        for (int j = 0; j < 4; j++){
          float v = acc[i][j][r];
          s1 += v; s2 += v * v;
        }
#pragma unroll
        for (int m = 1; m < 16; m <<= 1){
          s1 += __shfl_xor(s1, m, 64);
          s2 += __shfl_xor(s2, m, 64);
        }
        if (l16 == 0){
          int lr = i * 16 + half * 4 + r;
          part[lr * 4 + wave]       = s1;   // [0][lr][wave]
          part[256 + lr * 4 + wave] = s2;   // [1][lr][wave]
        }
      }
    }
    __syncthreads();
#pragma unroll
    for (int i = 0; i < 4; i++){
#pragma unroll
      for (int r = 0; r < 4; r++){
        int lr = i * 16 + half * 4 + r;
        int rg = row0 + lr;
        float4 p1 = *(const float4*)(part + lr * 4);
        float4 p2 = *(const float4*)(part + 256 + lr * 4);
        float su = p1.x + p1.y + p1.z + p1.w;
        float sq = p2.x + p2.y + p2.z + p2.w;
        float mean = su * (1.0f / 256.0f);
        float var = sq * (1.0f / 256.0f) - mean * mean;
        float rs = rsqrtf(var + 1e-5f);
        if (rg < M){
#pragma unroll
          for (int j = 0; j < 4; j++){
            int cg = wc + j * 16 + l16;
            float vv = (acc[i][j][r] - mean) * rs * lng[cg] + lnb[cg];
            out[(size_t)rg * 256 + cg] = vv;
          }
        }
      }
    }
  } else {
#pragma unroll
    for (int i = 0; i < 4; i++){
#pragma unroll
      for (int r = 0; r < 4; r++){
        int lr = i * 16 + half * 4 + r;
        int rg = row0 + lr;
        if (rg < M){
#pragma unroll
          for (int j = 0; j < 4; j++){
            int cg = wc + j * 16 + l16;
            out[(size_t)rg * 256 + cg] = acc[i][j][r];
          }
        }
      }
    }
  }
}

// helper: build CSR + aggregate mean for one stage
static void run_agg(const float* feat, const int* edge, int E, int Ndst,
                    int* cnt, int* row_start, int* fillc, int* bsums, int* esrc,
                    u16* mean, hipStream_t stream){
  const int* sidx = edge;
  const int* didx = edge + E;
  hipMemsetAsync(cnt, 0, (size_t)Ndst * 4, stream);
  hipMemsetAsync(fillc, 0, (size_t)Ndst * 4, stream);
  int egrid = (E + 255) / 256;
  hist_kernel<<<egrid, 256, 0, stream>>>(didx, E, cnt);
  int nb = (Ndst + 255) / 256;
  scan_block_kernel<<<nb, 256, 0, stream>>>(cnt, row_start, bsums, Ndst);
  scan_bsums_kernel<<<1, 512, 0, stream>>>(bsums, nb);
  scan_add_kernel<<<nb, 256, 0, stream>>>(row_start, bsums, Ndst);
  fill_csr_kernel<<<egrid, 256, 0, stream>>>(sidx, didx, E, row_start, fillc, esrc);
  agg_mean_kernel<<<(Ndst + 3) / 4, 256, 0, stream>>>(feat, row_start, cnt, esrc, mean, Ndst);
}

extern "C" void kernel_launch(void* const* d_in, const int* in_sizes, int n_in,
                              void* d_out, int out_size, void* d_ws, size_t ws_size,
                              hipStream_t stream){
  const float* cell_h = (const float*)d_in[0];
  const float* net_h  = (const float*)d_in[1];
  const int* e_c2n = (const int*)d_in[2];
  const int* e_n2c = (const int*)d_in[3];
  const int* e_c2c = (const int*)d_in[4];
  const float* w1p[3] = {(const float*)d_in[5], (const float*)d_in[9],  (const float*)d_in[13]};
  const float* b1p[3] = {(const float*)d_in[6], (const float*)d_in[10], (const float*)d_in[14]};
  const float* w2p[3] = {(const float*)d_in[7], (const float*)d_in[11], (const float*)d_in[15]};
  const float* b2p[3] = {(const float*)d_in[8], (const float*)d_in[12], (const float*)d_in[16]};
  const float* net_g  = (const float*)d_in[17];
  const float* net_b  = (const float*)d_in[18];
  const float* cell_g = (const float*)d_in[19];
  const float* cell_b = (const float*)d_in[20];

  int n_cell = in_sizes[0] / 256;
  int n_net  = in_sizes[1] / 256;
  int E = in_sizes[2] / 2;

  float* cell_out = (float*)d_out;
  float* net_out  = (float*)d_out + (size_t)n_cell * 256;

  // workspace layout
  char* p = (char*)d_ws;
  u16* w1t[3]; u16* w2t[3];
  for (int i = 0; i < 3; i++){
    w1t[i] = (u16*)p; p += (size_t)512 * 256 * 2;
    w2t[i] = (u16*)p; p += (size_t)256 * 256 * 2;
  }
  u16* Mbuf = (u16*)p; p += (size_t)n_cell * 256 * 2;  // bf16 mean
  int n_pad = ((n_cell + 63) / 64) * 64;
  int* cnt       = (int*)p; p += (size_t)n_pad * 4;
  int* row_start = (int*)p; p += (size_t)n_pad * 4;
  int* fillc     = (int*)p; p += (size_t)n_pad * 4;
  int* bsums     = (int*)p; p += 1024 * 4;
  int* esrc      = (int*)p; p += (size_t)E * 4;

  // convert + transpose weights to bf16 [N][K]
  for (int i = 0; i < 3; i++){
    conv_t_kernel<<<(512 * 256 + 255) / 256, 256, 0, stream>>>(w1p[i], w1t[i], 512, 256);
    conv_t_kernel<<<(256 * 256 + 255) / 256, 256, 0, stream>>>(w2p[i], w2t[i], 256, 256);
  }

  dim3 blk(256);

  // ---- stage 1: cells -> nets (LN) ----
  run_agg(cell_h, e_c2n, E, n_net, cnt, row_start, fillc, bsums, esrc, Mbuf, stream);
  fused_mlp_kernel<1><<<dim3((n_net + 63) / 64), blk, 0, stream>>>(
      net_h, Mbuf, w1t[0], b1p[0], w2t[0], b2p[0], net_h, net_g, net_b, net_out, n_net);

  // ---- stage 2: nets -> cells (no LN) ----
  run_agg(net_out, e_n2c, E, n_cell, cnt, row_start, fillc, bsums, esrc, Mbuf, stream);
  fused_mlp_kernel<0><<<dim3((n_cell + 63) / 64), blk, 0, stream>>>(
      cell_h, Mbuf, w1t[1], b1p[1], w2t[1], b2p[1], cell_h, nullptr, nullptr, cell_out, n_cell);

  // ---- stage 3: cells -> cells (LN), in-place on cell_out ----
  run_agg(cell_out, e_c2c, E, n_cell, cnt, row_start, fillc, bsums, esrc, Mbuf, stream);
  fused_mlp_kernel<1><<<dim3((n_cell + 63) / 64), blk, 0, stream>>>(
      cell_out, Mbuf, w1t[2], b1p[2], w2t[2], b2p[2], cell_out, cell_g, cell_b, cell_out, n_cell);
}

// Round 4
// 788.814 us; speedup vs baseline: 1.2574x; 1.0300x over previous
//
#include <hip/hip_runtime.h>
#include <stdint.h>

typedef unsigned short u16;
typedef short short8 __attribute__((ext_vector_type(8)));
typedef short short4v __attribute__((ext_vector_type(4)));
typedef float floatx4 __attribute__((ext_vector_type(4)));

#define D_FEAT 256

__device__ __forceinline__ u16 f2bf(float x){
  unsigned u = __float_as_uint(x);
  u += 0x7FFFu + ((u >> 16) & 1u);   // round-to-nearest-even
  return (u16)(u >> 16);
}

__device__ __forceinline__ short8 pack8(float4 a, float4 b){
  short8 v;
  v[0]=(short)f2bf(a.x); v[1]=(short)f2bf(a.y); v[2]=(short)f2bf(a.z); v[3]=(short)f2bf(a.w);
  v[4]=(short)f2bf(b.x); v[5]=(short)f2bf(b.y); v[6]=(short)f2bf(b.z); v[7]=(short)f2bf(b.w);
  return v;
}

// async global->LDS, 16B per lane; l must be wave-uniform base, g is per-lane
__device__ __forceinline__ void gload16(const void* g, void* l){
  __builtin_amdgcn_global_load_lds(
      (const __attribute__((address_space(1))) unsigned int*)g,
      (__attribute__((address_space(3))) unsigned int*)l, 16, 0, 0);
}

// Pre-swizzled bf16 weight layout for gload_lds staging (N=256 fixed):
// per K-step (32 k), 1024 slots of short8; slot s=(n<<2)|q holds chunk u=q^(n&3):
// wt[step*8192 + s*8 + e] = bf16(w[(k0+u*8+e)*256 + n])
__global__ void conv_swz_kernel(const float* __restrict__ w, u16* __restrict__ wt, int K){
  int idx = blockIdx.x * 256 + threadIdx.x;
  if (idx >= K * 256) return;
  int k = idx >> 8, n = idx & 255;
  int step = k >> 5, u = (k >> 3) & 3, e = k & 7;
  int q = u ^ (n & 3);
  wt[((size_t)step << 13) | (((n << 2) | q) << 3) | e] = f2bf(w[idx]);
}

// ---------------- CSR build ----------------
__global__ void hist_kernel(const int* __restrict__ didx, int E, int* __restrict__ cnt){
  int e = blockIdx.x * 256 + threadIdx.x;
  if (e < E) atomicAdd(&cnt[didx[e]], 1);
}

__global__ void scan_block_kernel(const int* __restrict__ cnt, int* __restrict__ excl,
                                  int* __restrict__ bsums, int N){
  __shared__ int tmp[256];
  int t = threadIdx.x;
  int i = blockIdx.x * 256 + t;
  int v = (i < N) ? cnt[i] : 0;
  tmp[t] = v; __syncthreads();
#pragma unroll
  for (int o = 1; o < 256; o <<= 1){
    int x = (t >= o) ? tmp[t - o] : 0;
    __syncthreads();
    tmp[t] += x;
    __syncthreads();
  }
  if (i < N) excl[i] = tmp[t] - v;
  if (t == 255) bsums[blockIdx.x] = tmp[255];
}

// parallel exclusive scan of block sums (nb <= 512 in practice; serial fallback otherwise)
__global__ void scan_bsums_kernel(int* __restrict__ bsums, int nb){
  __shared__ int tmp[512];
  int t = threadIdx.x;
  if (nb > 512){
    if (t == 0){
      int acc = 0;
      for (int i = 0; i < nb; i++){ int v = bsums[i]; bsums[i] = acc; acc += v; }
    }
    return;
  }
  int v = (t < nb) ? bsums[t] : 0;
  tmp[t] = v; __syncthreads();
#pragma unroll
  for (int o = 1; o < 512; o <<= 1){
    int x = (t >= o) ? tmp[t - o] : 0;
    __syncthreads();
    tmp[t] += x;
    __syncthreads();
  }
  if (t < nb) bsums[t] = tmp[t] - v;
}

// adds block offsets AND initializes fillc = row_start (removes fillc memset)
__global__ void scan_add_kernel(int* __restrict__ excl, const int* __restrict__ bsums,
                                int* __restrict__ fillc, int N){
  int i = blockIdx.x * 256 + threadIdx.x;
  if (i < N){
    int v = excl[i] + bsums[blockIdx.x];
    excl[i] = v;
    fillc[i] = v;
  }
}

// fillc holds absolute positions (pre-initialized to row_start)
__global__ void fill_csr_kernel(const int* __restrict__ sidx, const int* __restrict__ didx, int E,
                                int* __restrict__ fillc, int* __restrict__ esrc){
  int e = blockIdx.x * 256 + threadIdx.x;
  if (e >= E) return;
  int pos = atomicAdd(&fillc[didx[e]], 1);
  esrc[pos] = sidx[e];
}

// one wave per dst row: gather src rows, accumulate fp32, write mean as bf16
__global__ void agg_mean_kernel(const float* __restrict__ feat, const int* __restrict__ row_start,
                                const int* __restrict__ cnt, const int* __restrict__ esrc,
                                u16* __restrict__ mean, int M){
  int row = blockIdx.x * 4 + (threadIdx.x >> 6);
  int lane = threadIdx.x & 63;
  if (row >= M) return;
  int beg = row_start[row], n = cnt[row];
  float4 a0 = {0.f,0.f,0.f,0.f}, a1 = {0.f,0.f,0.f,0.f};
  int j = 0;
  for (; j + 1 < n; j += 2){
    int s0 = esrc[beg + j], s1 = esrc[beg + j + 1];
    float4 v0 = ((const float4*)(feat + (size_t)s0 * D_FEAT))[lane];
    float4 v1 = ((const float4*)(feat + (size_t)s1 * D_FEAT))[lane];
    a0.x += v0.x; a0.y += v0.y; a0.z += v0.z; a0.w += v0.w;
    a1.x += v1.x; a1.y += v1.y; a1.z += v1.z; a1.w += v1.w;
  }
  if (j < n){
    int s0 = esrc[beg + j];
    float4 v0 = ((const float4*)(feat + (size_t)s0 * D_FEAT))[lane];
    a0.x += v0.x; a0.y += v0.y; a0.z += v0.z; a0.w += v0.w;
  }
  float inv = 1.0f / fmaxf((float)n, 1.0f);
  short4v o;
  o[0] = (short)f2bf((a0.x + a1.x) * inv);
  o[1] = (short)f2bf((a0.y + a1.y) * inv);
  o[2] = (short)f2bf((a0.z + a1.z) * inv);
  o[3] = (short)f2bf((a0.w + a1.w) * inv);
  ((short4v*)(mean + (size_t)row * D_FEAT))[lane] = o;
}

// ---------------- Fused MLP: out = [LN]( resid + relu(concat(h,s)@W1+b1)@W2 + b2 ) ----------------
// Block: 64 rows x 256 cols, 256 threads (4 waves). LDS = 64 KB -> 2 blocks/CU.
// T3-minimum pipeline: ONE barrier per K-step; B staged via global_load_lds into a
// double buffer (weights pre-swizzled in global layout -> linear LDS dest, conflict-free
// swizzled reads); A reg-prefetched one step ahead, ds_written into As dbuf (aliases hid,
// which is dead during phase 1). LN `part` aliases Bs (dead in epilogue).
template<int HAS_LN>
__global__ __launch_bounds__(256, 2) void fused_mlp_kernel(
    const float* __restrict__ h, const u16* __restrict__ s,
    const u16* __restrict__ B1g, const float* __restrict__ b1,
    const u16* __restrict__ B2g, const float* __restrict__ b2,
    const float* __restrict__ resid,
    const float* __restrict__ lng, const float* __restrict__ lnb,
    float* __restrict__ out, int M)
{
  __shared__ __align__(16) char smem[65536];
  short8* Bs  = (short8*)smem;               // [2][1024]  32768 B dbuf
  u16*    hid = (u16*)(smem + 32768);        // [64*256]   32768 B (swizzled)
  short8* As  = (short8*)(smem + 32768);     // [2][256]    8192 B, aliases hid (phase-1 only)
  float*  part = (float*)smem;               // epilogue alias of Bs: [2][64][4]

  int tid = threadIdx.x;
  int wave = tid >> 6, lane = tid & 63;
  int half = lane >> 4, l16 = lane & 15;     // half in [0,4)
  int wc = wave * 64;
  int row0 = blockIdx.x * 64;

  int rA = tid >> 2, uA = tid & 3;
  int rgA = row0 + rA;
  bool rAok = rgA < M;
  int aw_slot = (rA << 2) | (uA ^ (rA & 3)); // swizzled A write slot

  floatx4 acc[4][4];
  floatx4 zero4 = {0.f, 0.f, 0.f, 0.f};
#pragma unroll
  for (int i = 0; i < 4; i++)
#pragma unroll
    for (int j = 0; j < 4; j++) acc[i][j] = zero4;

  short8 zero8 = {0,0,0,0,0,0,0,0};
  float4 pa0 = {0.f,0.f,0.f,0.f}, pa1 = {0.f,0.f,0.f,0.f};
  short8 ps = zero8;

  // ---- phase 1 prologue: B(step0) DMA, A(step0) load+write, A(step1) load ----
#pragma unroll
  for (int cc = 0; cc < 4; cc++){
    int base = cc * 256 + wc;
    gload16((const char*)B1g + ((size_t)(base + lane) << 4), Bs + base);
  }
  if (rAok){
    const float* src = h + (size_t)rgA * 256 + uA * 8;
    pa0 = ((const float4*)src)[0];
    pa1 = ((const float4*)src)[1];
  }
  As[aw_slot] = rAok ? pack8(pa0, pa1) : zero8;
  if (rAok){
    const float* src = h + (size_t)rgA * 256 + 32 + uA * 8;
    pa0 = ((const float4*)src)[0];
    pa1 = ((const float4*)src)[1];
  }
  __syncthreads();

  // ---- phase 1 main loop: hidden = relu(concat(h,s) @ W1 + b1), K=512, 1 barrier/step ----
  int cur = 0;
  for (int k0 = 0; k0 < 512; k0 += 32){
    int nxt = cur ^ 1;
    if (k0 < 480){
      int k1 = k0 + 32;
      int stepB = k1 >> 5;
#pragma unroll
      for (int cc = 0; cc < 4; cc++){
        int base = cc * 256 + wc;
        gload16((const char*)B1g + ((((size_t)stepB << 10) + base + lane) << 4),
                Bs + (nxt << 10) + base);
      }
      {
        short8 va = zero8;
        if (k1 < 256){ if (rAok) va = pack8(pa0, pa1); }
        else         { if (rAok) va = ps; }
        As[(nxt << 8) + aw_slot] = va;
      }
      int k2 = k1 + 32;
      if (k2 < 512 && rAok){
        int kk = k2 + uA * 8;
        if (k2 < 256){
          const float* src = h + (size_t)rgA * 256 + kk;
          pa0 = ((const float4*)src)[0];
          pa1 = ((const float4*)src)[1];
        } else {
          ps = *(const short8*)(s + (size_t)rgA * 256 + (kk - 256));
        }
      }
    }
    short8 af[4], bfr[4];
#pragma unroll
    for (int t = 0; t < 4; t++){
      int ra = t * 16 + l16;
      af[t] = As[(cur << 8) + ((ra << 2) | (half ^ (ra & 3)))];
      int rb = wc + t * 16 + l16;
      bfr[t] = Bs[(cur << 10) + ((rb << 2) | (half ^ (rb & 3)))];
    }
#pragma unroll
    for (int i = 0; i < 4; i++)
#pragma unroll
      for (int j = 0; j < 4; j++)
        acc[i][j] = __builtin_amdgcn_mfma_f32_16x16x32_bf16(af[i], bfr[j], acc[i][j], 0, 0, 0);
    __syncthreads();
    cur = nxt;
  }

  // ---- phase transition: issue B2(step0) DMA early, then spill hidden to LDS ----
#pragma unroll
  for (int cc = 0; cc < 4; cc++){
    int base = cc * 256 + wc;
    gload16((const char*)B2g + ((size_t)(base + lane) << 4), Bs + base);
  }
  // hidden -> LDS (bias + relu + bf16), swizzled: chunk ^= row&7  (clobbers As alias - dead)
#pragma unroll
  for (int i = 0; i < 4; i++){
#pragma unroll
    for (int j = 0; j < 4; j++){
      int cg = wc + j * 16 + l16;
      float bv = b1[cg];
#pragma unroll
      for (int r = 0; r < 4; r++){
        int lr = i * 16 + ((half & 1) ? 0 : 0) + half * 4 + r;  // half in [0,4): rows half*4+r
        int idx = lr * 256 + ((((cg >> 3) ^ (lr & 7)) << 3) | (cg & 7));
        hid[idx] = f2bf(fmaxf(acc[i][j][r] + bv, 0.0f));
      }
    }
  }
#pragma unroll
  for (int i = 0; i < 4; i++)
#pragma unroll
    for (int j = 0; j < 4; j++) acc[i][j] = zero4;
  __syncthreads();   // B2(0) arrived (vmcnt) + hid visible (lgkm)

  // ---- phase 2: out = hidden @ W2, K=256, 1 barrier/step ----
  cur = 0;
  for (int k0 = 0; k0 < 256; k0 += 32){
    int nxt = cur ^ 1;
    if (k0 < 224){
      int stepB = (k0 + 32) >> 5;
#pragma unroll
      for (int cc = 0; cc < 4; cc++){
        int base = cc * 256 + wc;
        gload16((const char*)B2g + ((((size_t)stepB << 10) + base + lane) << 4),
                Bs + (nxt << 10) + base);
      }
    }
    short8 af[4], bfr[4];
#pragma unroll
    for (int t = 0; t < 4; t++){
      int ra = t * 16 + l16;
      int chunkL = (k0 >> 3) + half;
      af[t] = *(const short8*)(hid + ra * 256 + ((chunkL ^ (ra & 7)) << 3));
      int rb = wc + t * 16 + l16;
      bfr[t] = Bs[(cur << 10) + ((rb << 2) | (half ^ (rb & 3)))];
    }
#pragma unroll
    for (int i = 0; i < 4; i++)
#pragma unroll
      for (int j = 0; j < 4; j++)
        acc[i][j] = __builtin_amdgcn_mfma_f32_16x16x32_bf16(af[i], bfr[j], acc[i][j], 0, 0, 0);
    __syncthreads();
    cur = nxt;
  }

  // ---- epilogue: bias + residual ----
#pragma unroll
  for (int i = 0; i < 4; i++){
#pragma unroll
    for (int j = 0; j < 4; j++){
      int cg = wc + j * 16 + l16;
      float bv = b2[cg];
#pragma unroll
      for (int r = 0; r < 4; r++){
        int lr = i * 16 + half * 4 + r;
        int rg = row0 + lr;
        float rv = (rg < M) ? resid[(size_t)rg * 256 + cg] : 0.0f;
        acc[i][j][r] = acc[i][j][r] + bv + rv;
      }
    }
  }

  if (HAS_LN){
#pragma unroll
    for (int i = 0; i < 4; i++){
#pragma unroll
      for (int r = 0; r < 4; r++){
        float s1 = 0.f, s2 = 0.f;
#pragma unroll
        for (int j = 0; j < 4; j++){
          float v = acc[i][j][r];
          s1 += v; s2 += v * v;
        }
#pragma unroll
        for (int m = 1; m < 16; m <<= 1){
          s1 += __shfl_xor(s1, m, 64);
          s2 += __shfl_xor(s2, m, 64);
        }
        if (l16 == 0){
          int lr = i * 16 + half * 4 + r;
          part[lr * 4 + wave]       = s1;
          part[256 + lr * 4 + wave] = s2;
        }
      }
    }
    __syncthreads();
#pragma unroll
    for (int i = 0; i < 4; i++){
#pragma unroll
      for (int r = 0; r < 4; r++){
        int lr = i * 16 + half * 4 + r;
        int rg = row0 + lr;
        float4 p1 = *(const float4*)(part + lr * 4);
        float4 p2 = *(const float4*)(part + 256 + lr * 4);
        float su = p1.x + p1.y + p1.z + p1.w;
        float sq = p2.x + p2.y + p2.z + p2.w;
        float mean = su * (1.0f / 256.0f);
        float var = sq * (1.0f / 256.0f) - mean * mean;
        float rs = rsqrtf(var + 1e-5f);
        if (rg < M){
#pragma unroll
          for (int j = 0; j < 4; j++){
            int cg = wc + j * 16 + l16;
            float vv = (acc[i][j][r] - mean) * rs * lng[cg] + lnb[cg];
            out[(size_t)rg * 256 + cg] = vv;
          }
        }
      }
    }
  } else {
#pragma unroll
    for (int i = 0; i < 4; i++){
#pragma unroll
      for (int r = 0; r < 4; r++){
        int lr = i * 16 + half * 4 + r;
        int rg = row0 + lr;
        if (rg < M){
#pragma unroll
          for (int j = 0; j < 4; j++){
            int cg = wc + j * 16 + l16;
            out[(size_t)rg * 256 + cg] = acc[i][j][r];
          }
        }
      }
    }
  }
}

// helper: build CSR + aggregate mean for one stage
static void run_agg(const float* feat, const int* edge, int E, int Ndst,
                    int* cnt, int* row_start, int* fillc, int* bsums, int* esrc,
                    u16* mean, hipStream_t stream){
  const int* sidx = edge;
  const int* didx = edge + E;
  hipMemsetAsync(cnt, 0, (size_t)Ndst * 4, stream);
  int egrid = (E + 255) / 256;
  hist_kernel<<<egrid, 256, 0, stream>>>(didx, E, cnt);
  int nb = (Ndst + 255) / 256;
  scan_block_kernel<<<nb, 256, 0, stream>>>(cnt, row_start, bsums, Ndst);
  scan_bsums_kernel<<<1, 512, 0, stream>>>(bsums, nb);
  scan_add_kernel<<<nb, 256, 0, stream>>>(row_start, bsums, fillc, Ndst);
  fill_csr_kernel<<<egrid, 256, 0, stream>>>(sidx, didx, E, fillc, esrc);
  agg_mean_kernel<<<(Ndst + 3) / 4, 256, 0, stream>>>(feat, row_start, cnt, esrc, mean, Ndst);
}

extern "C" void kernel_launch(void* const* d_in, const int* in_sizes, int n_in,
                              void* d_out, int out_size, void* d_ws, size_t ws_size,
                              hipStream_t stream){
  const float* cell_h = (const float*)d_in[0];
  const float* net_h  = (const float*)d_in[1];
  const int* e_c2n = (const int*)d_in[2];
  const int* e_n2c = (const int*)d_in[3];
  const int* e_c2c = (const int*)d_in[4];
  const float* w1p[3] = {(const float*)d_in[5], (const float*)d_in[9],  (const float*)d_in[13]};
  const float* b1p[3] = {(const float*)d_in[6], (const float*)d_in[10], (const float*)d_in[14]};
  const float* w2p[3] = {(const float*)d_in[7], (const float*)d_in[11], (const float*)d_in[15]};
  const float* b2p[3] = {(const float*)d_in[8], (const float*)d_in[12], (const float*)d_in[16]};
  const float* net_g  = (const float*)d_in[17];
  const float* net_b  = (const float*)d_in[18];
  const float* cell_g = (const float*)d_in[19];
  const float* cell_b = (const float*)d_in[20];

  int n_cell = in_sizes[0] / 256;
  int n_net  = in_sizes[1] / 256;
  int E = in_sizes[2] / 2;

  float* cell_out = (float*)d_out;
  float* net_out  = (float*)d_out + (size_t)n_cell * 256;

  // workspace layout
  char* p = (char*)d_ws;
  u16* w1t[3]; u16* w2t[3];
  for (int i = 0; i < 3; i++){
    w1t[i] = (u16*)p; p += (size_t)512 * 256 * 2;
    w2t[i] = (u16*)p; p += (size_t)256 * 256 * 2;
  }
  u16* Mbuf = (u16*)p; p += (size_t)n_cell * 256 * 2;  // bf16 mean
  int n_pad = ((n_cell + 63) / 64) * 64;
  int* cnt       = (int*)p; p += (size_t)n_pad * 4;
  int* row_start = (int*)p; p += (size_t)n_pad * 4;
  int* fillc     = (int*)p; p += (size_t)n_pad * 4;
  int* bsums     = (int*)p; p += 1024 * 4;
  int* esrc      = (int*)p; p += (size_t)E * 4;

  // convert weights to pre-swizzled bf16 gload_lds layout
  for (int i = 0; i < 3; i++){
    conv_swz_kernel<<<(512 * 256 + 255) / 256, 256, 0, stream>>>(w1p[i], w1t[i], 512);
    conv_swz_kernel<<<(256 * 256 + 255) / 256, 256, 0, stream>>>(w2p[i], w2t[i], 256);
  }

  dim3 blk(256);

  // ---- stage 1: cells -> nets (LN) ----
  run_agg(cell_h, e_c2n, E, n_net, cnt, row_start, fillc, bsums, esrc, Mbuf, stream);
  fused_mlp_kernel<1><<<dim3((n_net + 63) / 64), blk, 0, stream>>>(
      net_h, Mbuf, w1t[0], b1p[0], w2t[0], b2p[0], net_h, net_g, net_b, net_out, n_net);

  // ---- stage 2: nets -> cells (no LN) ----
  run_agg(net_out, e_n2c, E, n_cell, cnt, row_start, fillc, bsums, esrc, Mbuf, stream);
  fused_mlp_kernel<0><<<dim3((n_cell + 63) / 64), blk, 0, stream>>>(
      cell_h, Mbuf, w1t[1], b1p[1], w2t[1], b2p[1], cell_h, nullptr, nullptr, cell_out, n_cell);

  // ---- stage 3: cells -> cells (LN), in-place on cell_out ----
  run_agg(cell_out, e_c2c, E, n_cell, cnt, row_start, fillc, bsums, esrc, Mbuf, stream);
  fused_mlp_kernel<1><<<dim3((n_cell + 63) / 64), blk, 0, stream>>>(
      cell_out, Mbuf, w1t[2], b1p[2], w2t[2], b2p[2], cell_out, cell_g, cell_b, cell_out, n_cell);
}